// Round 24
// baseline (197.767 us; speedup 1.0000x reference)
//
#include <hip/hip_runtime.h>
#include <hip/hip_bf16.h>
#include <cmath>

#define DIM 512
#define HID 256
#define ROWS_PB 32       // rows per block (100000 = 3125 * 32, no tail)
#define NSTEP 8          // K steps of 64 (2 chunks of 32)
#define SB 32768         // B step bytes: 64k * 256c * 2B

typedef __attribute__((ext_vector_type(8))) short short8;
typedef __attribute__((ext_vector_type(4))) float f32x4;
typedef __attribute__((ext_vector_type(4))) unsigned int u32x4;

__device__ __forceinline__ unsigned short f2bf(float f) {
  union { float f; unsigned u; } v; v.f = f;
  unsigned u = v.u;
  return (unsigned short)((u + 0x7FFFu + ((u >> 16) & 1u)) >> 16);
}

// LDS-only barrier (R22/R23-verified): waits ds ops, syncs, fences the
// scheduler; does NOT drain vmcnt — reg-destined global loads survive.
#define LGKM_BAR()                                        \
  do {                                                    \
    asm volatile("s_waitcnt lgkmcnt(0)" ::: "memory");    \
    __builtin_amdgcn_s_barrier();                         \
    __builtin_amdgcn_sched_barrier(0);                    \
  } while (0)

// Pre-swizzle W1 (fp32 [512,256] row-major) into bf16 MFMA fragment order:
// w1s[((k>>3)*HID + c)*8 + (k&7)]. K-step i (64 k's) is the contiguous
// 32 KB at byte offset i*32768 — a linear copy.
__global__ void w1_swz_kernel(const float* __restrict__ W1,
                              unsigned short* __restrict__ w1s) {
  int tid = blockIdx.x * blockDim.x + threadIdx.x;
  if (tid >= DIM * HID) return;
  int k = tid / HID;
  int c = tid - k * HID;
  w1s[(((k >> 3) * HID) + c) * 8 + (k & 7)] = f2bf(W1[tid]);
}

__device__ __forceinline__ short8 cvt8(const f32x4 p0, const f32x4 p1) {
  short8 r;
  r[0] = (short)f2bf(p0[0]); r[1] = (short)f2bf(p0[1]);
  r[2] = (short)f2bf(p0[2]); r[3] = (short)f2bf(p0[3]);
  r[4] = (short)f2bf(p1[0]); r[5] = (short)f2bf(p1[1]);
  r[6] = (short)f2bf(p1[2]); r[7] = (short)f2bf(p1[3]);
  return r;
}

// R23 + BK=64 single-barrier steps: 8 barrier crossings per block instead
// of 32. Wave w: src s=w&1 (z1/z2), row-tile tl=w>>1 (16 rows, full HID).
// A streamed 2 steps ahead (32 regs, no long-lived af array). B: T14 breg
// staging into a DOUBLE-buffered 32 KB step buffer; BWRITE targets the
// buffer whose reads retired before the previous step's barrier -> one
// LGKM_BAR per step is sufficient ordering. Epilogue re-reads z from
// global (L2/L3-hot), fp32 end-to-end.
__global__ __launch_bounds__(256, 2) void fa_main_kernel(
    const float* __restrict__ z1, const float* __restrict__ z2,
    const unsigned short* __restrict__ w1s,
    const float* __restrict__ bias1, const float* __restrict__ W2,
    const float* __restrict__ bias2, float* __restrict__ out, int n) {
  __shared__ char smem[2 * SB + 256];     // B dbuf 64 KB; xs @ +65536
  float* xs = (float*)(smem + 2 * SB);    // [src][32 rows]

  const int t = threadIdx.x;
  const int w = t >> 6;
  const int l = t & 63;
  const int l15 = l & 15, l16 = l >> 4;
  const int s = w & 1;    // source
  const int tl = w >> 1;  // row tile 0..1
  const int row0 = blockIdx.x * ROWS_PB;
  const int myrow = row0 + tl * 16 + l15;
  const bool rok = myrow < n;
  const float* zz = s ? z2 : z1;
  const float* ap = zz + (size_t)myrow * DIM + (l16 << 3);
  const f32x4 zf4 = (f32x4){0.f, 0.f, 0.f, 0.f};

  // T14 B-staging: 32 KB/step = 8 x u32x4 per thread (wave-private regs).
  u32x4 br0, br1, br2, br3, br4, br5, br6, br7;
#define BLOAD(i)                                            \
  {                                                         \
    const u32x4* g = (const u32x4*)w1s + (i) * 2048 + t;    \
    br0 = g[0];    br1 = g[256];  br2 = g[512];  br3 = g[768]; \
    br4 = g[1024]; br5 = g[1280]; br6 = g[1536]; br7 = g[1792]; \
  }
#define BWRITE(buf)                                         \
  {                                                         \
    u32x4* d = (u32x4*)(smem + (buf) * SB) + t;             \
    d[0] = br0;    d[256] = br1;  d[512] = br2;  d[768] = br3; \
    d[1024] = br4; d[1280] = br5; d[1536] = br6; d[1792] = br7; \
  }

  // A-pipe: 2 slots x 4 f32x4 (steps i, i+1), statically rotated.
  f32x4 sA[4], sB[4];
#define ALOAD(i, slot)                                      \
  {                                                         \
    const float* p = ap + ((i) << 6);                       \
    slot[0] = rok ? *(const f32x4*)(p) : zf4;               \
    slot[1] = rok ? *(const f32x4*)(p + 4) : zf4;           \
    slot[2] = rok ? *(const f32x4*)(p + 32) : zf4;          \
    slot[3] = rok ? *(const f32x4*)(p + 36) : zf4;          \
  }

  // ---- Prologue: B step 0 + A steps 0,1; one full drain.
  BLOAD(0);
  ALOAD(0, sA);
  ALOAD(1, sB);
  BWRITE(0);
  __syncthreads();  // buf0 visible

  f32x4 acc[16];
#pragma unroll
  for (int f = 0; f < 16; ++f) acc[f] = zf4;

  // ---- K-loop: 8 steps, ONE LGKM_BAR each.
#pragma unroll
  for (int i = 0; i < NSTEP; ++i) {
    if (i + 1 < NSTEP) BLOAD(i + 1);  // L2 -> regs, survives the barrier
    short8 af0, af1;
    if (i & 1) {
      af0 = cvt8(sB[0], sB[1]);
      af1 = cvt8(sB[2], sB[3]);
    } else {
      af0 = cvt8(sA[0], sA[1]);
      af1 = cvt8(sA[2], sA[3]);
    }
    if (i + 2 < NSTEP) {  // refill the slot just consumed (HBM)
      if (i & 1) ALOAD(i + 2, sB) else ALOAD(i + 2, sA);
    }
    __builtin_amdgcn_sched_barrier(0);
    // Two chunks' fragment reads + MFMAs from buf[i&1].
    const short8* bp0 =
        (const short8*)(smem + (i & 1) * SB) + (l16 << 8) + l15;
    const short8* bp1 = bp0 + 1024;  // second chunk of the step (16 KB on)
#pragma unroll
    for (int f = 0; f < 16; ++f)
      acc[f] = __builtin_amdgcn_mfma_f32_16x16x32_bf16(af0, bp0[f << 4],
                                                       acc[f], 0, 0, 0);
#pragma unroll
    for (int f = 0; f < 16; ++f)
      acc[f] = __builtin_amdgcn_mfma_f32_16x16x32_bf16(af1, bp1[f << 4],
                                                       acc[f], 0, 0, 0);
    // BWRITE buf[(i+1)&1]: its readers (step i-1) retired before the
    // step i-1 barrier; we are past it -> safe. Own breg dependency is
    // handled by the compiler's vmcnt tracking.
    if (i + 1 < NSTEP) BWRITE((i + 1) & 1);
    LGKM_BAR();  // retires my reads+writes; syncs; vmem stays in flight
  }

  // ---- Logits. C/D: col = f*16+l15, row-in-tile = l16*4+r.
  float part[4] = {0.f, 0.f, 0.f, 0.f};
#pragma unroll
  for (int f = 0; f < 16; ++f) {
    const int cc = (f << 4) + l15;
    const float w2v = W2[cc];
    const float b1v = bias1[cc];
#pragma unroll
    for (int r = 0; r < 4; ++r) {
      const float hh = acc[f][r] + b1v;
      part[r] += (hh > 0.f) ? hh * w2v : 0.f;
    }
  }
#pragma unroll
  for (int r = 0; r < 4; ++r) {
#pragma unroll
    for (int m = 1; m < 16; m <<= 1) part[r] += __shfl_xor(part[r], m, 16);
  }
  if (l15 == 0) {
#pragma unroll
    for (int r = 0; r < 4; ++r)
      xs[s * ROWS_PB + tl * 16 + (l16 << 2) + r] = part[r];
  }
  __syncthreads();

  // ---- Epilogue: wave w rows w*8..+8; lane l cols l*4 and 256+l*4.
  // z re-read from global (L2/L3-hot), fp32 end-to-end (R15-proven).
#pragma unroll
  for (int j = 0; j < 8; ++j) {
    const int rl = (w << 3) + j;
    const int grow = row0 + rl;
    if (grow < n) {
      const float x = xs[rl];
      const float y = xs[ROWS_PB + rl];
      const float sx = 1.f / (1.f + __expf(y - x));  // b2 cancels
      const float sy = 1.f - sx;
      const size_t off = (size_t)grow * DIM + (l << 2);
#pragma unroll
      for (int half = 0; half < 2; ++half) {
        const size_t o = off + (half << 8);
        const f32x4 a4 = *(const f32x4*)(z1 + o);
        const f32x4 b4 = *(const f32x4*)(z2 + o);
        f32x4 ov;
        ov[0] = sx * a4[0] + sy * b4[0];
        ov[1] = sx * a4[1] + sy * b4[1];
        ov[2] = sx * a4[2] + sy * b4[2];
        ov[3] = sx * a4[3] + sy * b4[3];
        *(f32x4*)(out + o) = ov;
      }
    }
  }
#undef BLOAD
#undef BWRITE
#undef ALOAD
}

extern "C" void kernel_launch(void* const* d_in, const int* in_sizes, int n_in,
                              void* d_out, int out_size, void* d_ws,
                              size_t ws_size, hipStream_t stream) {
  const float* z1 = (const float*)d_in[0];
  const float* z2 = (const float*)d_in[1];
  const float* W1 = (const float*)d_in[2];
  const float* b1 = (const float*)d_in[3];
  const float* W2 = (const float*)d_in[4];
  const float* b2 = (const float*)d_in[5];
  float* out = (float*)d_out;
  const int n = in_sizes[0] / DIM;
  unsigned short* w1s = (unsigned short*)d_ws;  // 512*256*2 = 256 KB

  hipLaunchKernelGGL(w1_swz_kernel, dim3((DIM * HID + 255) / 256), dim3(256),
                     0, stream, W1, w1s);
  const int nwg = (n + ROWS_PB - 1) / ROWS_PB;
  hipLaunchKernelGGL(fa_main_kernel, dim3(nwg), dim3(256), 0, stream, z1, z2,
                     w1s, b1, W2, b2, out, n);
}